// Round 1
// baseline (76.510 us; speedup 1.0000x reference)
//
#include <hip/hip_runtime.h>

#define BATCH   8
#define HW      (1024 * 1024)
#define NA      512
#define EPSV    1e-8f
#define LAML    0.01f
#define LAMS    0.01f

#define BLOCKS_PER_BATCH 128
#define PIX_PER_BLOCK    (HW / BLOCKS_PER_BATCH)   // 8192
#define NVEC             (PIX_PER_BLOCK / 4)       // 2048 float4 per block
#define NBLOCKS          (BATCH * BLOCKS_PER_BATCH) // 1024

// Pass 1: per-(batch,admin) segment sums of score = (L+lamL)*(S+lamS).
__global__ __launch_bounds__(256) void k_sums(const float* __restrict__ lights,
                                              const float* __restrict__ settle,
                                              const int*   __restrict__ admin,
                                              float*       __restrict__ sums) {
    __shared__ float lsum[NA];
    const int tid = threadIdx.x;
    for (int i = tid; i < NA; i += 256) lsum[i] = 0.0f;
    __syncthreads();

    const int b     = blockIdx.x / BLOCKS_PER_BATCH;
    const int chunk = blockIdx.x % BLOCKS_PER_BATCH;
    const long base = (long)b * HW + (long)chunk * PIX_PER_BLOCK;

    const float4* __restrict__ L4 = (const float4*)(lights + base);
    const float4* __restrict__ S4 = (const float4*)(settle + base);
    const int4*   __restrict__ A4 = (const int4*)(admin + base);

    for (int v = tid; v < NVEC; v += 256) {
        float4 l = L4[v];
        float4 s = S4[v];
        int4   a = A4[v];
        atomicAdd(&lsum[a.x], (l.x + LAML) * (s.x + LAMS));
        atomicAdd(&lsum[a.y], (l.y + LAML) * (s.y + LAMS));
        atomicAdd(&lsum[a.z], (l.z + LAML) * (s.z + LAMS));
        atomicAdd(&lsum[a.w], (l.w + LAML) * (s.w + LAMS));
    }
    __syncthreads();

    for (int i = tid; i < NA; i += 256) {
        float v = lsum[i];
        if (v != 0.0f) atomicAdd(&sums[b * NA + i], v);
    }
}

// Pass 2: factor table per batch in LDS, recompute score, write out.
__global__ __launch_bounds__(256) void k_out(const float* __restrict__ lights,
                                             const float* __restrict__ settle,
                                             const int*   __restrict__ admin,
                                             const float* __restrict__ sums,
                                             const float* __restrict__ census,
                                             float*       __restrict__ out) {
    __shared__ float lfac[NA];
    const int tid = threadIdx.x;

    const int b     = blockIdx.x / BLOCKS_PER_BATCH;
    const int chunk = blockIdx.x % BLOCKS_PER_BATCH;

    for (int i = tid; i < NA; i += 256)
        lfac[i] = census[i] / (sums[b * NA + i] + EPSV);
    __syncthreads();

    const long base = (long)b * HW + (long)chunk * PIX_PER_BLOCK;
    const float4* __restrict__ L4 = (const float4*)(lights + base);
    const float4* __restrict__ S4 = (const float4*)(settle + base);
    const int4*   __restrict__ A4 = (const int4*)(admin + base);
    float4*       __restrict__ O4 = (float4*)(out + base);

    for (int v = tid; v < NVEC; v += 256) {
        float4 l = L4[v];
        float4 s = S4[v];
        int4   a = A4[v];
        float4 o;
        o.x = (l.x + LAML) * (s.x + LAMS) * lfac[a.x];
        o.y = (l.y + LAML) * (s.y + LAMS) * lfac[a.y];
        o.z = (l.z + LAML) * (s.z + LAMS) * lfac[a.z];
        o.w = (l.w + LAML) * (s.w + LAMS) * lfac[a.w];
        O4[v] = o;
    }
}

extern "C" void kernel_launch(void* const* d_in, const int* in_sizes, int n_in,
                              void* d_out, int out_size, void* d_ws, size_t ws_size,
                              hipStream_t stream) {
    const float* lights = (const float*)d_in[0];
    const float* settle = (const float*)d_in[1];
    const int*   admin  = (const int*)d_in[2];
    const float* census = (const float*)d_in[3];
    float*       out    = (float*)d_out;
    float*       sums   = (float*)d_ws;   // BATCH*NA floats

    // ws is poisoned (0xAA) and never re-poisoned between replays: zero it.
    hipMemsetAsync(sums, 0, BATCH * NA * sizeof(float), stream);

    k_sums<<<NBLOCKS, 256, 0, stream>>>(lights, settle, admin, sums);
    k_out<<<NBLOCKS, 256, 0, stream>>>(lights, settle, admin, sums, census, out);
}